// Round 5
// baseline (1475.601 us; speedup 1.0000x reference)
//
#include <hip/hip_runtime.h>
#include <stdint.h>

#define B_ 64
#define D_ 1024
#define H_ 1024
#define V_ 32000
#define T_ 20
#define SOS_ 0

typedef __attribute__((ext_vector_type(8))) __bf16 bf16x8;
typedef __attribute__((ext_vector_type(4))) float f32x4;

// ---------------------------------------------------------------- helpers
__device__ __forceinline__ uint32_t ord_of_float(float x) {
    uint32_t u = __float_as_uint(x);
    return (u & 0x80000000u) ? ~u : (u | 0x80000000u);
}

__device__ __forceinline__ unsigned long long shfl_xor_u64(unsigned long long x, int m) {
    return (unsigned long long)__shfl_xor((long long)x, m, 64);
}

// round-to-nearest-even fp32 -> bf16 split: f ~= hi + lo (each bf16)
__device__ __forceinline__ void split_bf16(float f, unsigned short* hi, unsigned short* lo) {
    uint32_t u = __float_as_uint(f);
    uint32_t rh = (u + 0x7FFFu + ((u >> 16) & 1u)) >> 16;
    *hi = (unsigned short)rh;
    float fl = f - __uint_as_float(rh << 16);
    uint32_t ul = __float_as_uint(fl);
    uint32_t rl = (ul + 0x7FFFu + ((ul >> 16) & 1u)) >> 16;
    *lo = (unsigned short)rl;
}

// async global -> LDS, 16 B per lane (dest is wave-uniform base + lane*16)
__device__ __forceinline__ void gload_lds16(const void* g, void* l) {
    __builtin_amdgcn_global_load_lds(
        (const __attribute__((address_space(1))) void*)g,
        (__attribute__((address_space(3))) void*)l, 16, 0, 0);
}

// ---------------------------------------------------------------- weight split (plain)
__global__ __launch_bounds__(256) void k_split_w(const float* __restrict__ src,
    unsigned short* __restrict__ hi, unsigned short* __restrict__ lo, int n4)
{
    int i = blockIdx.x * 256 + threadIdx.x;
    if (i >= n4) return;
    float4 v = ((const float4*)src)[i];
    ushort4 h, l;
    split_bf16(v.x, &h.x, &l.x);
    split_bf16(v.y, &h.y, &l.y);
    split_bf16(v.z, &h.z, &l.z);
    split_bf16(v.w, &h.w, &l.w);
    ((ushort4*)hi)[i] = h;
    ((ushort4*)lo)[i] = l;
}

// ---------------------------------------------------------------- weight split (gate-major permuted)
// Out row' = jt*48 + g*16 + jl  <->  in row = g*H + jt*16 + jl   (jt in [0,64))
__global__ __launch_bounds__(256) void k_split_w_perm(const float* __restrict__ src,
    unsigned short* __restrict__ hi, unsigned short* __restrict__ lo)
{
    int rp = blockIdx.x;                 // permuted row, 0..3071
    int jt = rp / 48;
    int rem = rp % 48;
    int g = rem >> 4;
    int jl = rem & 15;
    int orig = g * H_ + jt * 16 + jl;
    int c4 = threadIdx.x * 4;
    float4 v = *(const float4*)(src + (size_t)orig * H_ + c4);
    ushort4 h, l;
    split_bf16(v.x, &h.x, &l.x);
    split_bf16(v.y, &h.y, &l.y);
    split_bf16(v.z, &h.z, &l.z);
    split_bf16(v.w, &h.w, &l.w);
    *(ushort4*)(hi + (size_t)rp * H_ + c4) = h;
    *(ushort4*)(lo + (size_t)rp * H_ + c4) = l;
}

// ---------------------------------------------------------------- x prep (SOS)
__global__ __launch_bounds__(256) void k_prep_x0(const float* __restrict__ emb,
    unsigned short* __restrict__ xhi, unsigned short* __restrict__ xlo)
{
    int b = blockIdx.x;
    int tid = threadIdx.x;
    float4 v4 = *(const float4*)(emb + (size_t)SOS_ * H_ + tid * 4);
    ushort4 h, l;
    split_bf16(v4.x, &h.x, &l.x);
    split_bf16(v4.y, &h.y, &l.y);
    split_bf16(v4.z, &h.z, &l.z);
    split_bf16(v4.w, &h.w, &l.w);
    *(ushort4*)(xhi + (size_t)b * H_ + tid * 4) = h;
    *(ushort4*)(xlo + (size_t)b * H_ + tid * 4) = l;
}

// ---------------------------------------------------------------- init hidden (MFMA GEMM)
// h0 = latent @ Wp^T + bp.  16 blocks x (64b x 64j), K=1024.  Round-3 logits structure.
__global__ __launch_bounds__(256) void k_init_gemm(
    const unsigned short* __restrict__ lathi, const unsigned short* __restrict__ latlo,
    const unsigned short* __restrict__ wphi, const unsigned short* __restrict__ wplo,
    const float* __restrict__ bp, float* __restrict__ h0,
    unsigned short* __restrict__ hhi, unsigned short* __restrict__ hlo)
{
    __shared__ __align__(128) char Bsm[4][16384];
    int tid = threadIdx.x;
    int lane = tid & 63;
    int wv = tid >> 6;
    int row0 = blockIdx.x * 64;

    int r0 = wv * 8 + (lane >> 3);
    int r1 = r0 + 32;
    int kslt = (lane & 7) * 16;
    size_t so0 = (size_t)(row0 + r0) * 2048 + (size_t)(kslt ^ ((r0 & 7) << 4));
    size_t so1 = (size_t)(row0 + r1) * 2048 + (size_t)(kslt ^ ((r1 & 7) << 4));

    int mrow = wv * 16 + (lane & 15);
    int koff = (lane >> 4) * 8;
    int kb = koff * 2;

    f32x4 acc[4];
#pragma unroll
    for (int i = 0; i < 4; i++) acc[i] = (f32x4){0.f, 0.f, 0.f, 0.f};

    auto stage = [&](int BUF, int KC) {
        const char* bh = (const char*)wphi + (size_t)KC * 2;
        const char* bl = (const char*)wplo + (size_t)KC * 2;
        char* base = Bsm[BUF] + wv * 1024;
        gload_lds16(bh + so0, base);
        gload_lds16(bh + so1, base + 4096);
        gload_lds16(bl + so0, base + 8192);
        gload_lds16(bl + so1, base + 12288);
    };

    stage(0, 0);
    stage(1, 64);
    stage(2, 128);

    for (int it = 0; it < 16; ++it) {
        if (it == 0)      asm volatile("s_waitcnt vmcnt(8)"  ::: "memory");
        else if (it == 1) asm volatile("s_waitcnt vmcnt(12)" ::: "memory");
        else              asm volatile("s_waitcnt vmcnt(16)" ::: "memory");
        __builtin_amdgcn_s_barrier();
        __builtin_amdgcn_sched_barrier(0);
        int kc = it * 64;
        const unsigned short* ap  = lathi + (size_t)mrow * 1024 + kc + koff;
        const unsigned short* alp = latlo + (size_t)mrow * 1024 + kc + koff;
        bf16x8 ah0 = *(const bf16x8*)ap;
        bf16x8 ah1 = *(const bf16x8*)(ap + 32);
        bf16x8 al0 = *(const bf16x8*)alp;
        bf16x8 al1 = *(const bf16x8*)(alp + 32);
        const char* bhp = Bsm[it & 3];
        const char* blp = Bsm[it & 3] + 8192;
#pragma unroll
        for (int tv = 0; tv < 4; tv++) {
            int brow = tv * 16 + (lane & 15);
            int swz = (brow & 7) << 4;
            int ro = brow * 128;
            bf16x8 bh0 = *(const bf16x8*)(bhp + ro + (kb ^ swz));
            bf16x8 bh1 = *(const bf16x8*)(bhp + ro + ((kb + 64) ^ swz));
            bf16x8 bl0 = *(const bf16x8*)(blp + ro + (kb ^ swz));
            bf16x8 bl1 = *(const bf16x8*)(blp + ro + ((kb + 64) ^ swz));
            acc[tv] = __builtin_amdgcn_mfma_f32_16x16x32_bf16(ah0, bh0, acc[tv], 0, 0, 0);
            acc[tv] = __builtin_amdgcn_mfma_f32_16x16x32_bf16(ah1, bh1, acc[tv], 0, 0, 0);
            acc[tv] = __builtin_amdgcn_mfma_f32_16x16x32_bf16(al0, bh0, acc[tv], 0, 0, 0);
            acc[tv] = __builtin_amdgcn_mfma_f32_16x16x32_bf16(al1, bh1, acc[tv], 0, 0, 0);
            acc[tv] = __builtin_amdgcn_mfma_f32_16x16x32_bf16(ah0, bl0, acc[tv], 0, 0, 0);
            acc[tv] = __builtin_amdgcn_mfma_f32_16x16x32_bf16(ah1, bl1, acc[tv], 0, 0, 0);
        }
        if (it <= 12) stage((it + 3) & 3, (it + 3) * 64);
    }

    int col = lane & 15;
    int quad = lane >> 4;
#pragma unroll
    for (int tv = 0; tv < 4; tv++) {
        int j = row0 + tv * 16 + col;
        float bo = bp[j];
#pragma unroll
        for (int r = 0; r < 4; r++) {
            int b = wv * 16 + quad * 4 + r;
            float v = acc[tv][r] + bo;
            h0[(size_t)b * H_ + j] = v;
            unsigned short h_, l_;
            split_bf16(v, &h_, &l_);
            hhi[(size_t)b * H_ + j] = h_;
            hlo[(size_t)b * H_ + j] = l_;
        }
    }
}

// ---------------------------------------------------------------- fused gates GEMM + GRU elem
// 64 blocks, block jt owns j in [jt*16, jt*16+16).  Tile: 64b x 48cols(permuted r,z,n)
// x K=1024 for BOTH halves, interleaved (even iter = hh, odd = ih), kc=128.
// 4-buffer counted-vmcnt pipeline; 16-slot XOR swizzle on 256 B LDS rows.
// Epilogue applies GRU gate math in-register and writes hnext + split planes.
struct AF8 { bf16x8 h[4]; bf16x8 l[4]; };

#define GMMA(AV, ACC, BUFPTR) do {                                              \
    const char* _bp = (BUFPTR);                                                 \
    _Pragma("unroll")                                                           \
    for (int tv = 0; tv < 3; tv++) {                                            \
        int brow = tv * 16 + (lane & 15);                                       \
        int sw = (brow & 15) << 4;                                              \
        const char* rh = _bp + brow * 256;                                      \
        const char* rl = _bp + 12288 + brow * 256;                              \
        _Pragma("unroll")                                                       \
        for (int ks = 0; ks < 4; ks++) {                                        \
            bf16x8 bh = *(const bf16x8*)(rh + ((ks * 64 + kb) ^ sw));           \
            bf16x8 bl = *(const bf16x8*)(rl + ((ks * 64 + kb) ^ sw));           \
            ACC[tv] = __builtin_amdgcn_mfma_f32_16x16x32_bf16(AV.h[ks], bh, ACC[tv], 0, 0, 0); \
            ACC[tv] = __builtin_amdgcn_mfma_f32_16x16x32_bf16(AV.l[ks], bh, ACC[tv], 0, 0, 0); \
            ACC[tv] = __builtin_amdgcn_mfma_f32_16x16x32_bf16(AV.h[ks], bl, ACC[tv], 0, 0, 0); \
        }                                                                       \
    }                                                                           \
} while (0)

__global__ __launch_bounds__(256) void k_gru_step(
    const unsigned short* __restrict__ xhi, const unsigned short* __restrict__ xlo,
    const unsigned short* __restrict__ hphi, const unsigned short* __restrict__ hplo,
    const unsigned short* __restrict__ wihh, const unsigned short* __restrict__ wihl,
    const unsigned short* __restrict__ whhh, const unsigned short* __restrict__ whhl,
    const float* __restrict__ bih, const float* __restrict__ bhh,
    const float* __restrict__ hprev, float* __restrict__ hnext,
    unsigned short* __restrict__ hnhi, unsigned short* __restrict__ hnlo)
{
    __shared__ __align__(128) char Bsm[4][24576];   // 96 KiB: [buf][hi 12K | lo 12K]
    int tid = threadIdx.x;
    int lane = tid & 63;
    int wv = tid >> 6;
    int jt = blockIdx.x;                 // 0..63
    int prow0 = jt * 48;                 // permuted-W row base

    int mrow = wv * 16 + (lane & 15);    // b row for A frags
    int koff = (lane >> 4) * 8;          // elements within 32-k slice
    int kb = koff * 2;                   // bytes {0,16,32,48}

    f32x4 acc_h[3], acc_i[3];
#pragma unroll
    for (int i = 0; i < 3; i++) {
        acc_h[i] = (f32x4){0.f, 0.f, 0.f, 0.f};
        acc_i[i] = (f32x4){0.f, 0.f, 0.f, 0.f};
    }

    // stage s in [0,16): half = s&1 (0=hh,1=ih), kc = (s>>1)*128.
    // 24 chunks of 1 KiB (4 rows x 256 B); wave w does chunks w+4m, m in [0,6).
    auto stageG = [&](int s) {
        const unsigned short* PH = (s & 1) ? wihh : whhh;
        const unsigned short* PL = (s & 1) ? wihl : whhl;
        size_t kcb = (size_t)((s >> 1) * 128) * 2;
#pragma unroll
        for (int m = 0; m < 6; m++) {
            int c = wv + m * 4;
            const unsigned short* P = (c < 12) ? PH : PL;
            int row = (c % 12) * 4 + (lane >> 4);
            int slot = (lane & 15) * 16;
            size_t off = (size_t)(prow0 + row) * 2048 + kcb
                       + (size_t)(slot ^ ((row & 15) << 4));
            gload_lds16((const char*)P + off, Bsm[s & 3] + c * 1024);
        }
    };

    auto loadA8 = [&](const unsigned short* Phi, const unsigned short* Plo, int kc) {
        AF8 f;
#pragma unroll
        for (int ks = 0; ks < 4; ks++) {
            f.h[ks] = *(const bf16x8*)(Phi + (size_t)mrow * 1024 + kc + ks * 32 + koff);
            f.l[ks] = *(const bf16x8*)(Plo + (size_t)mrow * 1024 + kc + ks * 32 + koff);
        }
        return f;
    };

    // prologue: 3 stages (6 gloads each) + A_h(0) (8 loads)
    stageG(0);
    stageG(1);
    stageG(2);
    __builtin_amdgcn_sched_barrier(0);
    AF8 Ah = loadA8(hphi, hplo, 0);
    AF8 Ao;
    __builtin_amdgcn_sched_barrier(0);

    for (int i2 = 0; i2 < 16; i2 += 2) {
        int kc = (i2 >> 1) * 128;
        // ---- even body i=i2 (hh) ----
        // ledger (younger than stage(i2)'s last load): i2=0 -> 20; i2=14 -> 22; else 28
        if (i2 == 0)       asm volatile("s_waitcnt vmcnt(20)" ::: "memory");
        else if (i2 == 14) asm volatile("s_waitcnt vmcnt(22)" ::: "memory");
        else               asm volatile("s_waitcnt vmcnt(28)" ::: "memory");
        __builtin_amdgcn_s_barrier();
        __builtin_amdgcn_sched_barrier(0);
        Ao = loadA8(xhi, xlo, kc);           // A for odd body (ih), same kc
        __builtin_amdgcn_sched_barrier(0);
        if (i2 + 3 < 16) stageG(i2 + 3);
        __builtin_amdgcn_sched_barrier(0);
        GMMA(Ah, acc_h, Bsm[i2 & 3]);

        // ---- odd body i=i2+1 (ih) ----
        // ledger: i=15 -> 16; else 28
        if (i2 + 1 == 15) asm volatile("s_waitcnt vmcnt(16)" ::: "memory");
        else              asm volatile("s_waitcnt vmcnt(28)" ::: "memory");
        __builtin_amdgcn_s_barrier();
        __builtin_amdgcn_sched_barrier(0);
        if (i2 + 2 < 16) Ah = loadA8(hphi, hplo, kc + 128);
        __builtin_amdgcn_sched_barrier(0);
        if (i2 + 4 < 16) stageG(i2 + 4);
        __builtin_amdgcn_sched_barrier(0);
        GMMA(Ao, acc_i, Bsm[(i2 + 1) & 3]);
    }

    // ---- fused GRU elementwise ----
    // acc_*[tv][r]: tv = gate (0=r,1=z,2=n), col j_local = lane&15, b = wv*16+(lane>>4)*4+r
    int jl = lane & 15;
    int quad = lane >> 4;
    int j = jt * 16 + jl;
    float bir = bih[j],        bhr = bhh[j];
    float biz = bih[H_ + j],   bhz = bhh[H_ + j];
    float bin = bih[2 * H_ + j], bhn = bhh[2 * H_ + j];
#pragma unroll
    for (int r = 0; r < 4; r++) {
        int b = wv * 16 + quad * 4 + r;
        float ir = acc_i[0][r] + bir;
        float iz = acc_i[1][r] + biz;
        float in_ = acc_i[2][r] + bin;
        float hr = acc_h[0][r] + bhr;
        float hz = acc_h[1][r] + bhz;
        float hn = acc_h[2][r] + bhn;
        float rg = 1.f / (1.f + expf(-(ir + hr)));
        float z  = 1.f / (1.f + expf(-(iz + hz)));
        float n  = tanhf(in_ + rg * hn);
        float hpv = hprev[(size_t)b * H_ + j];
        float v = (1.f - z) * n + z * hpv;
        hnext[(size_t)b * H_ + j] = v;
        unsigned short h_, l_;
        split_bf16(v, &h_, &l_);
        hnhi[(size_t)b * H_ + j] = h_;
        hnlo[(size_t)b * H_ + j] = l_;
    }
}

// ---------------------------------------------------------------- logits + argmax (round-4)
__global__ __launch_bounds__(256) void k_logits_argmax2(
    const unsigned short* __restrict__ hhi, const unsigned short* __restrict__ hlo,
    const unsigned short* __restrict__ wouth, const unsigned short* __restrict__ woutl,
    const float* __restrict__ bout, unsigned long long* __restrict__ partials,
    int nblk)
{
    __shared__ __align__(128) char Bsm[4][16384];
    int tid = threadIdx.x;
    int lane = tid & 63;
    int wv = tid >> 6;
    int row0 = blockIdx.x * 64;   // vbase

    int r0 = wv * 8 + (lane >> 3);
    int r1 = r0 + 32;
    int kslt = (lane & 7) * 16;
    size_t so0 = (size_t)(row0 + r0) * 2048 + (size_t)(kslt ^ ((r0 & 7) << 4));
    size_t so1 = (size_t)(row0 + r1) * 2048 + (size_t)(kslt ^ ((r1 & 7) << 4));

    int mrow = wv * 16 + (lane & 15);
    int koff = (lane >> 4) * 8;
    int kb = koff * 2;

    f32x4 acc[4];
#pragma unroll
    for (int i = 0; i < 4; i++) acc[i] = (f32x4){0.f, 0.f, 0.f, 0.f};

    auto stage = [&](int BUF, int KC) {
        const char* bh = (const char*)wouth + (size_t)KC * 2;
        const char* bl = (const char*)woutl + (size_t)KC * 2;
        char* base = Bsm[BUF] + wv * 1024;
        gload_lds16(bh + so0, base);
        gload_lds16(bh + so1, base + 4096);
        gload_lds16(bl + so0, base + 8192);
        gload_lds16(bl + so1, base + 12288);
    };

    struct AF { bf16x8 h0, h1, l0, l1; };
    auto loadA = [&](int kc) {
        AF f;
        const unsigned short* ap  = hhi + (size_t)mrow * 1024 + kc + koff;
        const unsigned short* alp = hlo + (size_t)mrow * 1024 + kc + koff;
        f.h0 = *(const bf16x8*)ap;
        f.h1 = *(const bf16x8*)(ap + 32);
        f.l0 = *(const bf16x8*)alp;
        f.l1 = *(const bf16x8*)(alp + 32);
        return f;
    };
    auto mmaBlk = [&](const AF& a, const char* bhp, const char* blp) {
#pragma unroll
        for (int tv = 0; tv < 4; tv++) {
            int brow = tv * 16 + (lane & 15);
            int swz = (brow & 7) << 4;
            int ro = brow * 128;
            bf16x8 bh0 = *(const bf16x8*)(bhp + ro + (kb ^ swz));
            bf16x8 bh1 = *(const bf16x8*)(bhp + ro + ((kb + 64) ^ swz));
            bf16x8 bl0 = *(const bf16x8*)(blp + ro + (kb ^ swz));
            bf16x8 bl1 = *(const bf16x8*)(blp + ro + ((kb + 64) ^ swz));
            acc[tv] = __builtin_amdgcn_mfma_f32_16x16x32_bf16(a.h0, bh0, acc[tv], 0, 0, 0);
            acc[tv] = __builtin_amdgcn_mfma_f32_16x16x32_bf16(a.h1, bh1, acc[tv], 0, 0, 0);
            acc[tv] = __builtin_amdgcn_mfma_f32_16x16x32_bf16(a.l0, bh0, acc[tv], 0, 0, 0);
            acc[tv] = __builtin_amdgcn_mfma_f32_16x16x32_bf16(a.l1, bh1, acc[tv], 0, 0, 0);
            acc[tv] = __builtin_amdgcn_mfma_f32_16x16x32_bf16(a.h0, bl0, acc[tv], 0, 0, 0);
            acc[tv] = __builtin_amdgcn_mfma_f32_16x16x32_bf16(a.h1, bl1, acc[tv], 0, 0, 0);
        }
    };

    stage(0, 0);
    stage(1, 64);
    stage(2, 128);
    __builtin_amdgcn_sched_barrier(0);
    AF Ae = loadA(0);
    AF Ao;
    __builtin_amdgcn_sched_barrier(0);

    for (int it2 = 0; it2 < 16; it2 += 2) {
        if (it2 == 0 || it2 == 14) asm volatile("s_waitcnt vmcnt(0)" ::: "memory");
        else                       asm volatile("s_waitcnt vmcnt(4)" ::: "memory");
        __builtin_amdgcn_s_barrier();
        __builtin_amdgcn_sched_barrier(0);
        Ao = loadA((it2 + 1) * 64);
        __builtin_amdgcn_sched_barrier(0);
        if (it2 <= 12) stage((it2 + 3) & 3, (it2 + 3) * 64);
        __builtin_amdgcn_sched_barrier(0);
        mmaBlk(Ae, Bsm[it2 & 3], Bsm[it2 & 3] + 8192);

        if (it2 + 1 >= 14) asm volatile("s_waitcnt vmcnt(0)" ::: "memory");
        else               asm volatile("s_waitcnt vmcnt(4)" ::: "memory");
        __builtin_amdgcn_s_barrier();
        __builtin_amdgcn_sched_barrier(0);
        if (it2 + 2 < 16) Ae = loadA((it2 + 2) * 64);
        __builtin_amdgcn_sched_barrier(0);
        if (it2 + 1 <= 12) stage((it2 + 4) & 3, (it2 + 4) * 64);
        __builtin_amdgcn_sched_barrier(0);
        mmaBlk(Ao, Bsm[(it2 + 1) & 3], Bsm[(it2 + 1) & 3] + 8192);
    }

    int col = lane & 15;
    int quad = lane >> 4;
    unsigned long long kmax[4] = {0ull, 0ull, 0ull, 0ull};
#pragma unroll
    for (int tv = 0; tv < 4; tv++) {
        int v = row0 + tv * 16 + col;
        float bo = bout[v];
#pragma unroll
        for (int r = 0; r < 4; r++) {
            float lg = acc[tv][r] + bo;
            unsigned long long key = ((unsigned long long)ord_of_float(lg) << 32)
                                   | (unsigned long long)(0x7FFFFFFFu - (uint32_t)v);
            if (key > kmax[r]) kmax[r] = key;
        }
    }
#pragma unroll
    for (int r = 0; r < 4; r++) {
        unsigned long long k = kmax[r];
#pragma unroll
        for (int off = 1; off < 16; off <<= 1) {
            unsigned long long o = shfl_xor_u64(k, off);
            if (o > k) k = o;
        }
        kmax[r] = k;
    }
    if (col == 0) {
#pragma unroll
        for (int r = 0; r < 4; r++) {
            int b = wv * 16 + quad * 4 + r;
            partials[(size_t)b * nblk + blockIdx.x] = kmax[r];
        }
    }
}

// ---------------------------------------------------------------- token reduce + next-x prep
__global__ __launch_bounds__(256) void k_token2(
    const unsigned long long* __restrict__ partials, int nblk,
    int* __restrict__ tok, float* __restrict__ out_tokens, int t,
    const float* __restrict__ emb,
    unsigned short* __restrict__ xhi, unsigned short* __restrict__ xlo)
{
    __shared__ int s_tok;
    int b = blockIdx.x;
    int tid = threadIdx.x;
    if (tid < 64) {
        unsigned long long k = 0ull;
        for (int i = tid; i < nblk; i += 64) {
            unsigned long long p = partials[(size_t)b * nblk + i];
            if (p > k) k = p;
        }
#pragma unroll
        for (int off = 32; off; off >>= 1) {
            unsigned long long o = shfl_xor_u64(k, off);
            if (o > k) k = o;
        }
        if (tid == 0) {
            int v = (int)(0x7FFFFFFFu - (uint32_t)(k & 0xFFFFFFFFull));
            tok[b] = v;
            out_tokens[b * T_ + t] = (float)v;
            s_tok = v;
        }
    }
    __syncthreads();
    int row = s_tok;
    float4 v4 = *(const float4*)(emb + (size_t)row * H_ + tid * 4);
    ushort4 h, l;
    split_bf16(v4.x, &h.x, &l.x);
    split_bf16(v4.y, &h.y, &l.y);
    split_bf16(v4.z, &h.z, &l.z);
    split_bf16(v4.w, &h.w, &l.w);
    *(ushort4*)(xhi + (size_t)b * H_ + tid * 4) = h;
    *(ushort4*)(xlo + (size_t)b * H_ + tid * 4) = l;
}

// ---------------------------------------------------------------- final h copy
__global__ __launch_bounds__(256) void k_copy_h(const float* __restrict__ h,
                                               float* __restrict__ out)
{
    int i = (blockIdx.x * 256 + threadIdx.x) * 4;
    *(float4*)(out + i) = *(const float4*)(h + i);
}

// ---------------------------------------------------------------- launch
extern "C" void kernel_launch(void* const* d_in, const int* in_sizes, int n_in,
                              void* d_out, int out_size, void* d_ws, size_t ws_size,
                              hipStream_t stream)
{
    const float* latent = (const float*)d_in[0];
    const float* Wp     = (const float*)d_in[1];
    const float* bp     = (const float*)d_in[2];
    const float* emb    = (const float*)d_in[3];
    const float* Wih    = (const float*)d_in[4];
    const float* bih    = (const float*)d_in[5];
    const float* Whh    = (const float*)d_in[6];
    const float* bhh    = (const float*)d_in[7];
    const float* Wout   = (const float*)d_in[8];
    const float* bout   = (const float*)d_in[9];
    float* out = (float*)d_out;

    char* ws = (char*)d_ws;
    // ---- workspace layout ----
    float* h0   = (float*)(ws + 0);                              // 256 KiB
    float* h1   = (float*)(ws + 262144);                         // 256 KiB
    int* tok    = (int*)(ws + 524288);                           // 1 KiB
    unsigned long long* partials = (unsigned long long*)(ws + 525312);  // 256 KiB
    unsigned short* hhi0 = (unsigned short*)(ws + 787456);       // 128 KiB each
    unsigned short* hlo0 = (unsigned short*)(ws + 918528);
    unsigned short* hhi1 = (unsigned short*)(ws + 1049600);
    unsigned short* hlo1 = (unsigned short*)(ws + 1180672);
    unsigned short* xhi  = (unsigned short*)(ws + 1311744);
    unsigned short* xlo  = (unsigned short*)(ws + 1442816);
    unsigned short* lathi = (unsigned short*)(ws + 1573888);     // 128 KiB each
    unsigned short* latlo = (unsigned short*)(ws + 1704960);
    unsigned short* wphi  = (unsigned short*)(ws + 1836032);     // 2 MiB each
    unsigned short* wplo  = (unsigned short*)(ws + 3933184);
    unsigned short* wihh = (unsigned short*)(ws + 6030336);      // 6 MiB each (permuted)
    unsigned short* wihl = (unsigned short*)(ws + 12321792);
    unsigned short* whhh = (unsigned short*)(ws + 18613248);
    unsigned short* whhl = (unsigned short*)(ws + 24904704);
    unsigned short* wouth = (unsigned short*)(ws + 31196160);    // 62.5 MiB each
    unsigned short* woutl = (unsigned short*)(ws + 96732160);    // end ~154.8 MiB

    const int NBLK = V_ / 64;   // 500

    // one-time splits
    k_split_w_perm<<<3072, 256, 0, stream>>>(Wih, wihh, wihl);
    k_split_w_perm<<<3072, 256, 0, stream>>>(Whh, whhh, whhl);
    k_split_w<<<32000, 256, 0, stream>>>(Wout, wouth, woutl, V_ * H_ / 4);
    k_split_w<<<1024, 256, 0, stream>>>(Wp, wphi, wplo, H_ * D_ / 4);
    k_split_w<<<64, 256, 0, stream>>>(latent, lathi, latlo, B_ * D_ / 4);

    k_init_gemm<<<16, 256, 0, stream>>>(lathi, latlo, wphi, wplo, bp, h0, hhi0, hlo0);
    k_prep_x0<<<64, 256, 0, stream>>>(emb, xhi, xlo);

    float* hp = h0;  unsigned short* hphi = hhi0;  unsigned short* hplo = hlo0;
    float* hn = h1;  unsigned short* hnhi = hhi1;  unsigned short* hnlo = hlo1;
    for (int t = 0; t < T_; t++) {
        k_gru_step<<<64, 256, 0, stream>>>(xhi, xlo, hphi, hplo,
                                           wihh, wihl, whhh, whhl,
                                           bih, bhh, hp, hn, hnhi, hnlo);
        k_logits_argmax2<<<NBLK, 256, 0, stream>>>(hnhi, hnlo, wouth, woutl,
                                                   bout, partials, NBLK);
        k_token2<<<B_, 256, 0, stream>>>(partials, NBLK, tok, out, t, emb, xhi, xlo);
        { float* tf = hp; hp = hn; hn = tf; }
        { unsigned short* ts = hphi; hphi = hnhi; hnhi = ts; }
        { unsigned short* ts = hplo; hplo = hnlo; hnlo = ts; }
    }
    k_copy_h<<<64, 256, 0, stream>>>(hp, out + B_ * T_);
}

// Round 6
// 1203.586 us; speedup vs baseline: 1.2260x; 1.2260x over previous
//
#include <hip/hip_runtime.h>
#include <stdint.h>

#define B_ 64
#define D_ 1024
#define H_ 1024
#define V_ 32000
#define T_ 20
#define SOS_ 0

typedef __attribute__((ext_vector_type(8))) __bf16 bf16x8;
typedef __attribute__((ext_vector_type(4))) float f32x4;

// ---------------------------------------------------------------- helpers
__device__ __forceinline__ uint32_t ord_of_float(float x) {
    uint32_t u = __float_as_uint(x);
    return (u & 0x80000000u) ? ~u : (u | 0x80000000u);
}

__device__ __forceinline__ unsigned long long shfl_xor_u64(unsigned long long x, int m) {
    return (unsigned long long)__shfl_xor((long long)x, m, 64);
}

// round-to-nearest-even fp32 -> bf16 split: f ~= hi + lo (each bf16)
__device__ __forceinline__ void split_bf16(float f, unsigned short* hi, unsigned short* lo) {
    uint32_t u = __float_as_uint(f);
    uint32_t rh = (u + 0x7FFFu + ((u >> 16) & 1u)) >> 16;
    *hi = (unsigned short)rh;
    float fl = f - __uint_as_float(rh << 16);
    uint32_t ul = __float_as_uint(fl);
    uint32_t rl = (ul + 0x7FFFu + ((ul >> 16) & 1u)) >> 16;
    *lo = (unsigned short)rl;
}

// async global -> LDS, 16 B per lane (dest is wave-uniform base + lane*16)
__device__ __forceinline__ void gload_lds16(const void* g, void* l) {
    __builtin_amdgcn_global_load_lds(
        (const __attribute__((address_space(1))) void*)g,
        (__attribute__((address_space(3))) void*)l, 16, 0, 0);
}

// ---------------------------------------------------------------- weight split
__global__ __launch_bounds__(256) void k_split_w(const float* __restrict__ src,
    unsigned short* __restrict__ hi, unsigned short* __restrict__ lo, int n4)
{
    int i = blockIdx.x * 256 + threadIdx.x;
    if (i >= n4) return;
    float4 v = ((const float4*)src)[i];
    ushort4 h, l;
    split_bf16(v.x, &h.x, &l.x);
    split_bf16(v.y, &h.y, &l.y);
    split_bf16(v.z, &h.z, &l.z);
    split_bf16(v.w, &h.w, &l.w);
    ((ushort4*)hi)[i] = h;
    ((ushort4*)lo)[i] = l;
}

// ---------------------------------------------------------------- x prep (SOS)
__global__ __launch_bounds__(256) void k_prep_x0(const float* __restrict__ emb,
    unsigned short* __restrict__ xhi, unsigned short* __restrict__ xlo)
{
    int b = blockIdx.x;
    int tid = threadIdx.x;
    float4 v4 = *(const float4*)(emb + (size_t)SOS_ * H_ + tid * 4);
    ushort4 h, l;
    split_bf16(v4.x, &h.x, &l.x);
    split_bf16(v4.y, &h.y, &l.y);
    split_bf16(v4.z, &h.z, &l.z);
    split_bf16(v4.w, &h.w, &l.w);
    *(ushort4*)(xhi + (size_t)b * H_ + tid * 4) = h;
    *(ushort4*)(xlo + (size_t)b * H_ + tid * 4) = l;
}

// ---------------------------------------------------------------- init hidden (MFMA GEMM)
// h0 = latent @ Wp^T + bp.  16 blocks x (64b x 64j), K=1024.
__global__ __launch_bounds__(256) void k_init_gemm(
    const unsigned short* __restrict__ lathi, const unsigned short* __restrict__ latlo,
    const unsigned short* __restrict__ wphi, const unsigned short* __restrict__ wplo,
    const float* __restrict__ bp, float* __restrict__ h0,
    unsigned short* __restrict__ hhi, unsigned short* __restrict__ hlo)
{
    __shared__ __align__(128) char Bsm[4][16384];
    int tid = threadIdx.x;
    int lane = tid & 63;
    int wv = tid >> 6;
    int row0 = blockIdx.x * 64;

    int r0 = wv * 8 + (lane >> 3);
    int r1 = r0 + 32;
    int kslt = (lane & 7) * 16;
    size_t so0 = (size_t)(row0 + r0) * 2048 + (size_t)(kslt ^ ((r0 & 7) << 4));
    size_t so1 = (size_t)(row0 + r1) * 2048 + (size_t)(kslt ^ ((r1 & 7) << 4));

    int mrow = wv * 16 + (lane & 15);
    int koff = (lane >> 4) * 8;
    int kb = koff * 2;

    f32x4 acc[4];
#pragma unroll
    for (int i = 0; i < 4; i++) acc[i] = (f32x4){0.f, 0.f, 0.f, 0.f};

    auto stage = [&](int BUF, int KC) {
        const char* bh = (const char*)wphi + (size_t)KC * 2;
        const char* bl = (const char*)wplo + (size_t)KC * 2;
        char* base = Bsm[BUF] + wv * 1024;
        gload_lds16(bh + so0, base);
        gload_lds16(bh + so1, base + 4096);
        gload_lds16(bl + so0, base + 8192);
        gload_lds16(bl + so1, base + 12288);
    };

    stage(0, 0);
    stage(1, 64);
    stage(2, 128);

    for (int it = 0; it < 16; ++it) {
        if (it == 0)      asm volatile("s_waitcnt vmcnt(8)"  ::: "memory");
        else if (it == 1) asm volatile("s_waitcnt vmcnt(12)" ::: "memory");
        else              asm volatile("s_waitcnt vmcnt(16)" ::: "memory");
        __builtin_amdgcn_s_barrier();
        __builtin_amdgcn_sched_barrier(0);
        int kc = it * 64;
        const unsigned short* ap  = lathi + (size_t)mrow * 1024 + kc + koff;
        const unsigned short* alp = latlo + (size_t)mrow * 1024 + kc + koff;
        bf16x8 ah0 = *(const bf16x8*)ap;
        bf16x8 ah1 = *(const bf16x8*)(ap + 32);
        bf16x8 al0 = *(const bf16x8*)alp;
        bf16x8 al1 = *(const bf16x8*)(alp + 32);
        const char* bhp = Bsm[it & 3];
        const char* blp = Bsm[it & 3] + 8192;
#pragma unroll
        for (int tv = 0; tv < 4; tv++) {
            int brow = tv * 16 + (lane & 15);
            int swz = (brow & 7) << 4;
            int ro = brow * 128;
            bf16x8 bh0 = *(const bf16x8*)(bhp + ro + (kb ^ swz));
            bf16x8 bh1 = *(const bf16x8*)(bhp + ro + ((kb + 64) ^ swz));
            bf16x8 bl0 = *(const bf16x8*)(blp + ro + (kb ^ swz));
            bf16x8 bl1 = *(const bf16x8*)(blp + ro + ((kb + 64) ^ swz));
            acc[tv] = __builtin_amdgcn_mfma_f32_16x16x32_bf16(ah0, bh0, acc[tv], 0, 0, 0);
            acc[tv] = __builtin_amdgcn_mfma_f32_16x16x32_bf16(ah1, bh1, acc[tv], 0, 0, 0);
            acc[tv] = __builtin_amdgcn_mfma_f32_16x16x32_bf16(al0, bh0, acc[tv], 0, 0, 0);
            acc[tv] = __builtin_amdgcn_mfma_f32_16x16x32_bf16(al1, bh1, acc[tv], 0, 0, 0);
            acc[tv] = __builtin_amdgcn_mfma_f32_16x16x32_bf16(ah0, bl0, acc[tv], 0, 0, 0);
            acc[tv] = __builtin_amdgcn_mfma_f32_16x16x32_bf16(ah1, bl1, acc[tv], 0, 0, 0);
        }
        if (it <= 12) stage((it + 3) & 3, (it + 3) * 64);
    }

    int col = lane & 15;
    int quad = lane >> 4;
#pragma unroll
    for (int tv = 0; tv < 4; tv++) {
        int j = row0 + tv * 16 + col;
        float bo = bp[j];
#pragma unroll
        for (int r = 0; r < 4; r++) {
            int b = wv * 16 + quad * 4 + r;
            float v = acc[tv][r] + bo;
            h0[(size_t)b * H_ + j] = v;
            unsigned short h_, l_;
            split_bf16(v, &h_, &l_);
            hhi[(size_t)b * H_ + j] = h_;
            hlo[(size_t)b * H_ + j] = l_;
        }
    }
}

// ---------------------------------------------------------------- gates GEMM (round-4)
// Grid 384: jt(48) x half(2) x ks(4).  All A fragments + all 4 stages upfront;
// counted waits 12/8/4/0 (A loads oldest -> retire first, no hidden drain).
__global__ __launch_bounds__(256) void k_gates_gemm2(
    const unsigned short* __restrict__ xhi, const unsigned short* __restrict__ xlo,
    const unsigned short* __restrict__ hhi, const unsigned short* __restrict__ hlo,
    const unsigned short* __restrict__ wihh, const unsigned short* __restrict__ wihl,
    const unsigned short* __restrict__ whhh, const unsigned short* __restrict__ whhl,
    float* __restrict__ gbuf)
{
    __shared__ __align__(128) char Bsm[4][16384];
    int tid = threadIdx.x;
    int lane = tid & 63;
    int wv = tid >> 6;
    int blk = blockIdx.x;
    int jt = blk % 48;
    int rest = blk / 48;
    int half = rest & 1;
    int ks = rest >> 1;
    int kbase = ks * 256;
    int row0 = jt * 64;

    const unsigned short* Ahi_g = half ? hhi : xhi;
    const unsigned short* Alo_g = half ? hlo : xlo;
    const unsigned short* Bhi_g = half ? whhh : wihh;
    const unsigned short* Blo_g = half ? whhl : wihl;

    int r0 = wv * 8 + (lane >> 3);
    int r1 = r0 + 32;
    int kslt = (lane & 7) * 16;
    size_t so0 = (size_t)(row0 + r0) * 2048 + (size_t)(kslt ^ ((r0 & 7) << 4));
    size_t so1 = (size_t)(row0 + r1) * 2048 + (size_t)(kslt ^ ((r1 & 7) << 4));

    int mrow = wv * 16 + (lane & 15);
    int koff = (lane >> 4) * 8;
    int kb = koff * 2;

    f32x4 acc[4];
#pragma unroll
    for (int i = 0; i < 4; i++) acc[i] = (f32x4){0.f, 0.f, 0.f, 0.f};

    bf16x8 AH0[4], AH1[4], AL0[4], AL1[4];
#pragma unroll
    for (int it = 0; it < 4; it++) {
        int kc = kbase + it * 64;
        const unsigned short* ap  = Ahi_g + (size_t)mrow * 1024 + kc + koff;
        const unsigned short* alp = Alo_g + (size_t)mrow * 1024 + kc + koff;
        AH0[it] = *(const bf16x8*)ap;
        AH1[it] = *(const bf16x8*)(ap + 32);
        AL0[it] = *(const bf16x8*)alp;
        AL1[it] = *(const bf16x8*)(alp + 32);
    }
    __builtin_amdgcn_sched_barrier(0);

    auto stage = [&](int BUF, int KC) {
        const char* bh = (const char*)Bhi_g + (size_t)KC * 2;
        const char* bl = (const char*)Blo_g + (size_t)KC * 2;
        char* base = Bsm[BUF] + wv * 1024;
        gload_lds16(bh + so0, base);
        gload_lds16(bh + so1, base + 4096);
        gload_lds16(bl + so0, base + 8192);
        gload_lds16(bl + so1, base + 12288);
    };

    stage(0, kbase);
    stage(1, kbase + 64);
    stage(2, kbase + 128);
    stage(3, kbase + 192);
    __builtin_amdgcn_sched_barrier(0);

#pragma unroll
    for (int it = 0; it < 4; ++it) {
        if (it == 0)      asm volatile("s_waitcnt vmcnt(12)" ::: "memory");
        else if (it == 1) asm volatile("s_waitcnt vmcnt(8)"  ::: "memory");
        else if (it == 2) asm volatile("s_waitcnt vmcnt(4)"  ::: "memory");
        else              asm volatile("s_waitcnt vmcnt(0)"  ::: "memory");
        __builtin_amdgcn_s_barrier();
        __builtin_amdgcn_sched_barrier(0);
        const char* bhp = Bsm[it];
        const char* blp = Bsm[it] + 8192;
#pragma unroll
        for (int tv = 0; tv < 4; tv++) {
            int brow = tv * 16 + (lane & 15);
            int swz = (brow & 7) << 4;
            int ro = brow * 128;
            bf16x8 bh0 = *(const bf16x8*)(bhp + ro + (kb ^ swz));
            bf16x8 bh1 = *(const bf16x8*)(bhp + ro + ((kb + 64) ^ swz));
            bf16x8 bl0 = *(const bf16x8*)(blp + ro + (kb ^ swz));
            bf16x8 bl1 = *(const bf16x8*)(blp + ro + ((kb + 64) ^ swz));
            acc[tv] = __builtin_amdgcn_mfma_f32_16x16x32_bf16(AH0[it], bh0, acc[tv], 0, 0, 0);
            acc[tv] = __builtin_amdgcn_mfma_f32_16x16x32_bf16(AH1[it], bh1, acc[tv], 0, 0, 0);
            acc[tv] = __builtin_amdgcn_mfma_f32_16x16x32_bf16(AL0[it], bh0, acc[tv], 0, 0, 0);
            acc[tv] = __builtin_amdgcn_mfma_f32_16x16x32_bf16(AL1[it], bh1, acc[tv], 0, 0, 0);
            acc[tv] = __builtin_amdgcn_mfma_f32_16x16x32_bf16(AH0[it], bl0, acc[tv], 0, 0, 0);
            acc[tv] = __builtin_amdgcn_mfma_f32_16x16x32_bf16(AH1[it], bl1, acc[tv], 0, 0, 0);
        }
    }

    int col = lane & 15;
    int quad = lane >> 4;
    float* og = gbuf + (size_t)((ks * 2 + half) * 64) * 3072;
#pragma unroll
    for (int tv = 0; tv < 4; tv++) {
#pragma unroll
        for (int r = 0; r < 4; r++) {
            int b = wv * 16 + quad * 4 + r;
            og[(size_t)b * 3072 + jt * 64 + tv * 16 + col] = acc[tv][r];
        }
    }
}

// ---------------------------------------------------------------- gate elementwise
__global__ __launch_bounds__(256) void k_gru_elem2(
    const float* __restrict__ gbuf, const float* __restrict__ bih,
    const float* __restrict__ bhh, const float* __restrict__ hprev,
    float* __restrict__ hnext, unsigned short* __restrict__ hnhi,
    unsigned short* __restrict__ hnlo)
{
    int idx = blockIdx.x * 256 + threadIdx.x;
    int b = idx >> 10;
    int j = idx & 1023;
    float ir = bih[j], hr = bhh[j];
    float iz = bih[H_ + j], hz = bhh[H_ + j];
    float in_ = bih[2 * H_ + j], hn = bhh[2 * H_ + j];
#pragma unroll
    for (int ks = 0; ks < 4; ks++) {
        const float* gi = gbuf + (size_t)(ks * 2 * 64 + b) * 3072;
        const float* gh = gbuf + (size_t)((ks * 2 + 1) * 64 + b) * 3072;
        ir += gi[j];          hr += gh[j];
        iz += gi[H_ + j];     hz += gh[H_ + j];
        in_ += gi[2 * H_ + j]; hn += gh[2 * H_ + j];
    }
    float r = 1.f / (1.f + expf(-(ir + hr)));
    float z = 1.f / (1.f + expf(-(iz + hz)));
    float n = tanhf(in_ + r * hn);
    float hp = hprev[idx];
    float v = (1.f - z) * n + z * hp;
    hnext[idx] = v;
    unsigned short h_, l_;
    split_bf16(v, &h_, &l_);
    hnhi[idx] = h_;
    hnlo[idx] = l_;
}

// ---------------------------------------------------------------- logits + argmax
// 4-buffer stage pipeline (3 ahead) + depth-2 A-register prefetch (A[3], fully
// unrolled -> static indices).  Per-iter issue order: wait, A(it+2), stage(it+3),
// MFMA.  Exact vmcnt ledger: {it0:4, it1:8, it2..13:12, it14:8, it15:0}.
__global__ __launch_bounds__(256) void k_logits_argmax3(
    const unsigned short* __restrict__ hhi, const unsigned short* __restrict__ hlo,
    const unsigned short* __restrict__ wouth, const unsigned short* __restrict__ woutl,
    const float* __restrict__ bout, unsigned long long* __restrict__ partials,
    int nblk)
{
    __shared__ __align__(128) char Bsm[4][16384];
    int tid = threadIdx.x;
    int lane = tid & 63;
    int wv = tid >> 6;
    int row0 = blockIdx.x * 64;

    int r0 = wv * 8 + (lane >> 3);
    int r1 = r0 + 32;
    int kslt = (lane & 7) * 16;
    size_t so0 = (size_t)(row0 + r0) * 2048 + (size_t)(kslt ^ ((r0 & 7) << 4));
    size_t so1 = (size_t)(row0 + r1) * 2048 + (size_t)(kslt ^ ((r1 & 7) << 4));

    int mrow = wv * 16 + (lane & 15);
    int koff = (lane >> 4) * 8;
    int kb = koff * 2;

    f32x4 acc[4];
#pragma unroll
    for (int i = 0; i < 4; i++) acc[i] = (f32x4){0.f, 0.f, 0.f, 0.f};

    auto stage = [&](int BUF, int KC) {
        const char* bh = (const char*)wouth + (size_t)KC * 2;
        const char* bl = (const char*)woutl + (size_t)KC * 2;
        char* base = Bsm[BUF] + wv * 1024;
        gload_lds16(bh + so0, base);
        gload_lds16(bh + so1, base + 4096);
        gload_lds16(bl + so0, base + 8192);
        gload_lds16(bl + so1, base + 12288);
    };

    struct AF { bf16x8 h0, h1, l0, l1; };
    auto loadA = [&](int kc) {
        AF f;
        const unsigned short* ap  = hhi + (size_t)mrow * 1024 + kc + koff;
        const unsigned short* alp = hlo + (size_t)mrow * 1024 + kc + koff;
        f.h0 = *(const bf16x8*)ap;
        f.h1 = *(const bf16x8*)(ap + 32);
        f.l0 = *(const bf16x8*)alp;
        f.l1 = *(const bf16x8*)(alp + 32);
        return f;
    };
    auto mmaBlk = [&](const AF& a, const char* bhp, const char* blp) {
#pragma unroll
        for (int tv = 0; tv < 4; tv++) {
            int brow = tv * 16 + (lane & 15);
            int swz = (brow & 7) << 4;
            int ro = brow * 128;
            bf16x8 bh0 = *(const bf16x8*)(bhp + ro + (kb ^ swz));
            bf16x8 bh1 = *(const bf16x8*)(bhp + ro + ((kb + 64) ^ swz));
            bf16x8 bl0 = *(const bf16x8*)(blp + ro + (kb ^ swz));
            bf16x8 bl1 = *(const bf16x8*)(blp + ro + ((kb + 64) ^ swz));
            acc[tv] = __builtin_amdgcn_mfma_f32_16x16x32_bf16(a.h0, bh0, acc[tv], 0, 0, 0);
            acc[tv] = __builtin_amdgcn_mfma_f32_16x16x32_bf16(a.h1, bh1, acc[tv], 0, 0, 0);
            acc[tv] = __builtin_amdgcn_mfma_f32_16x16x32_bf16(a.l0, bh0, acc[tv], 0, 0, 0);
            acc[tv] = __builtin_amdgcn_mfma_f32_16x16x32_bf16(a.l1, bh1, acc[tv], 0, 0, 0);
            acc[tv] = __builtin_amdgcn_mfma_f32_16x16x32_bf16(a.h0, bl0, acc[tv], 0, 0, 0);
            acc[tv] = __builtin_amdgcn_mfma_f32_16x16x32_bf16(a.h1, bl1, acc[tv], 0, 0, 0);
        }
    };

    // prologue: 3 stages + A0,A1 (depth-2).  Order pinned.
    stage(0, 0);
    stage(1, 64);
    stage(2, 128);
    __builtin_amdgcn_sched_barrier(0);
    AF A[3];
    A[0] = loadA(0);
    A[1] = loadA(64);
    __builtin_amdgcn_sched_barrier(0);

#pragma unroll
    for (int it = 0; it < 16; ++it) {
        if (it == 15)                 asm volatile("s_waitcnt vmcnt(0)"  ::: "memory");
        else if (it == 0)             asm volatile("s_waitcnt vmcnt(4)"  ::: "memory");
        else if (it == 1 || it == 14) asm volatile("s_waitcnt vmcnt(8)"  ::: "memory");
        else                          asm volatile("s_waitcnt vmcnt(12)" ::: "memory");
        __builtin_amdgcn_s_barrier();
        __builtin_amdgcn_sched_barrier(0);
        if (it + 2 < 16) A[(it + 2) % 3] = loadA((it + 2) * 64);
        __builtin_amdgcn_sched_barrier(0);
        if (it + 3 < 16) stage((it + 3) & 3, (it + 3) * 64);
        __builtin_amdgcn_sched_barrier(0);
        mmaBlk(A[it % 3], Bsm[it & 3], Bsm[it & 3] + 8192);
    }

    int col = lane & 15;
    int quad = lane >> 4;
    unsigned long long kmax[4] = {0ull, 0ull, 0ull, 0ull};
#pragma unroll
    for (int tv = 0; tv < 4; tv++) {
        int v = row0 + tv * 16 + col;
        float bo = bout[v];
#pragma unroll
        for (int r = 0; r < 4; r++) {
            float lg = acc[tv][r] + bo;
            unsigned long long key = ((unsigned long long)ord_of_float(lg) << 32)
                                   | (unsigned long long)(0x7FFFFFFFu - (uint32_t)v);
            if (key > kmax[r]) kmax[r] = key;
        }
    }
#pragma unroll
    for (int r = 0; r < 4; r++) {
        unsigned long long k = kmax[r];
#pragma unroll
        for (int off = 1; off < 16; off <<= 1) {
            unsigned long long o = shfl_xor_u64(k, off);
            if (o > k) k = o;
        }
        kmax[r] = k;
    }
    if (col == 0) {
#pragma unroll
        for (int r = 0; r < 4; r++) {
            int b = wv * 16 + quad * 4 + r;
            partials[(size_t)b * nblk + blockIdx.x] = kmax[r];
        }
    }
}

// ---------------------------------------------------------------- token reduce + next-x prep
__global__ __launch_bounds__(256) void k_token2(
    const unsigned long long* __restrict__ partials, int nblk,
    int* __restrict__ tok, float* __restrict__ out_tokens, int t,
    const float* __restrict__ emb,
    unsigned short* __restrict__ xhi, unsigned short* __restrict__ xlo)
{
    __shared__ int s_tok;
    int b = blockIdx.x;
    int tid = threadIdx.x;
    if (tid < 64) {
        unsigned long long k = 0ull;
        for (int i = tid; i < nblk; i += 64) {
            unsigned long long p = partials[(size_t)b * nblk + i];
            if (p > k) k = p;
        }
#pragma unroll
        for (int off = 32; off; off >>= 1) {
            unsigned long long o = shfl_xor_u64(k, off);
            if (o > k) k = o;
        }
        if (tid == 0) {
            int v = (int)(0x7FFFFFFFu - (uint32_t)(k & 0xFFFFFFFFull));
            tok[b] = v;
            out_tokens[b * T_ + t] = (float)v;
            s_tok = v;
        }
    }
    __syncthreads();
    int row = s_tok;
    float4 v4 = *(const float4*)(emb + (size_t)row * H_ + tid * 4);
    ushort4 h, l;
    split_bf16(v4.x, &h.x, &l.x);
    split_bf16(v4.y, &h.y, &l.y);
    split_bf16(v4.z, &h.z, &l.z);
    split_bf16(v4.w, &h.w, &l.w);
    *(ushort4*)(xhi + (size_t)b * H_ + tid * 4) = h;
    *(ushort4*)(xlo + (size_t)b * H_ + tid * 4) = l;
}

// ---------------------------------------------------------------- final h copy
__global__ __launch_bounds__(256) void k_copy_h(const float* __restrict__ h,
                                               float* __restrict__ out)
{
    int i = (blockIdx.x * 256 + threadIdx.x) * 4;
    *(float4*)(out + i) = *(const float4*)(h + i);
}

// ---------------------------------------------------------------- launch
extern "C" void kernel_launch(void* const* d_in, const int* in_sizes, int n_in,
                              void* d_out, int out_size, void* d_ws, size_t ws_size,
                              hipStream_t stream)
{
    const float* latent = (const float*)d_in[0];
    const float* Wp     = (const float*)d_in[1];
    const float* bp     = (const float*)d_in[2];
    const float* emb    = (const float*)d_in[3];
    const float* Wih    = (const float*)d_in[4];
    const float* bih    = (const float*)d_in[5];
    const float* Whh    = (const float*)d_in[6];
    const float* bhh    = (const float*)d_in[7];
    const float* Wout   = (const float*)d_in[8];
    const float* bout   = (const float*)d_in[9];
    float* out = (float*)d_out;

    char* ws = (char*)d_ws;
    // ---- workspace layout ----
    float* h0   = (float*)(ws + 0);                              // 256 KiB
    float* h1   = (float*)(ws + 262144);                         // 256 KiB
    int* tok    = (int*)(ws + 524288);                           // 1 KiB
    unsigned long long* partials = (unsigned long long*)(ws + 525312);  // 256 KiB
    float* gbuf = (float*)(ws + 787456);                         // 6 MiB
    unsigned short* hhi0 = (unsigned short*)(ws + 7078912);      // 128 KiB each
    unsigned short* hlo0 = (unsigned short*)(ws + 7209984);
    unsigned short* hhi1 = (unsigned short*)(ws + 7341056);
    unsigned short* hlo1 = (unsigned short*)(ws + 7472128);
    unsigned short* xhi  = (unsigned short*)(ws + 7603200);
    unsigned short* xlo  = (unsigned short*)(ws + 7734272);
    unsigned short* lathi = (unsigned short*)(ws + 7865344);     // 128 KiB each
    unsigned short* latlo = (unsigned short*)(ws + 7996416);
    unsigned short* wphi  = (unsigned short*)(ws + 8127488);     // 2 MiB each
    unsigned short* wplo  = (unsigned short*)(ws + 10224640);
    unsigned short* wihh = (unsigned short*)(ws + 12321792);     // 6 MiB each
    unsigned short* wihl = (unsigned short*)(ws + 18613248);
    unsigned short* whhh = (unsigned short*)(ws + 24904704);
    unsigned short* whhl = (unsigned short*)(ws + 31196160);
    unsigned short* wouth = (unsigned short*)(ws + 37487616);    // 62.5 MiB each
    unsigned short* woutl = (unsigned short*)(ws + 103023616);   // end ~160.8 MiB

    const int NBLK = V_ / 64;   // 500

    // one-time splits
    k_split_w<<<3072, 256, 0, stream>>>(Wih, wihh, wihl, 3 * H_ * H_ / 4);
    k_split_w<<<3072, 256, 0, stream>>>(Whh, whhh, whhl, 3 * H_ * H_ / 4);
    k_split_w<<<32000, 256, 0, stream>>>(Wout, wouth, woutl, V_ * H_ / 4);
    k_split_w<<<1024, 256, 0, stream>>>(Wp, wphi, wplo, H_ * D_ / 4);
    k_split_w<<<64, 256, 0, stream>>>(latent, lathi, latlo, B_ * D_ / 4);

    k_init_gemm<<<16, 256, 0, stream>>>(lathi, latlo, wphi, wplo, bp, h0, hhi0, hlo0);
    k_prep_x0<<<64, 256, 0, stream>>>(emb, xhi, xlo);

    float* hp = h0;  unsigned short* hphi = hhi0;  unsigned short* hplo = hlo0;
    float* hn = h1;  unsigned short* hnhi = hhi1;  unsigned short* hnlo = hlo1;
    for (int t = 0; t < T_; t++) {
        k_gates_gemm2<<<384, 256, 0, stream>>>(xhi, xlo, hphi, hplo,
                                               wihh, wihl, whhh, whhl, gbuf);
        k_gru_elem2<<<256, 256, 0, stream>>>(gbuf, bih, bhh, hp, hn, hnhi, hnlo);
        k_logits_argmax3<<<NBLK, 256, 0, stream>>>(hnhi, hnlo, wouth, woutl,
                                                   bout, partials, NBLK);
        k_token2<<<B_, 256, 0, stream>>>(partials, NBLK, tok, out, t, emb, xhi, xlo);
        { float* tf = hp; hp = hn; hn = tf; }
        { unsigned short* ts = hphi; hphi = hnhi; hnhi = ts; }
        { unsigned short* ts = hplo; hplo = hnlo; hnlo = ts; }
    }
    k_copy_h<<<64, 256, 0, stream>>>(hp, out + B_ * T_);
}